// Round 1
// baseline (583.782 us; speedup 1.0000x reference)
//
#include <hip/hip_runtime.h>

#define SDIM 196
#define BDIM 64
#define NDIM 512
#define DDIM 1024
#define HDIM 8

typedef __attribute__((ext_vector_type(8))) short short8;
typedef __attribute__((ext_vector_type(8))) unsigned short ushort8;
typedef __attribute__((ext_vector_type(4))) unsigned short ushort4v;
typedef __attribute__((ext_vector_type(4))) float f32x4;

typedef const __attribute__((address_space(1))) unsigned int* gq_ptr;
typedef __attribute__((address_space(3))) unsigned int* lds_ptr;

__device__ __forceinline__ unsigned short f2bf(float f) {
    unsigned int x = __float_as_uint(f);
    x += 0x7fffu + ((x >> 16) & 1u);   // RNE
    return (unsigned short)(x >> 16);
}

__device__ __forceinline__ float wred_sum(float v) {
#pragma unroll
    for (int off = 32; off > 0; off >>= 1) v += __shfl_down(v, off);
    return v;
}

// ---------------- input -> bf16 copy + partial sums over s (7 chunks of 28) ----------------
__global__ __launch_bounds__(256) void k_mean_cast(const float* __restrict__ in,
                                                   unsigned short* __restrict__ Abf,
                                                   float* __restrict__ gpart) {
    int idx4 = blockIdx.x * 256 + threadIdx.x;   // 0..16383 over B*D/4
    int z = blockIdx.y;                           // 0..6
    size_t base = (size_t)idx4 * 4;
    float4 acc = make_float4(0.f, 0.f, 0.f, 0.f);
    int s0 = z * 28;
    for (int s = s0; s < s0 + 28; s++) {
        float4 v = *(const float4*)(in + (size_t)s * 65536 + base);
        acc.x += v.x; acc.y += v.y; acc.z += v.z; acc.w += v.w;
        ushort4v u;
        u[0] = f2bf(v.x); u[1] = f2bf(v.y); u[2] = f2bf(v.z); u[3] = f2bf(v.w);
        *(ushort4v*)(Abf + (size_t)s * 65536 + base) = u;
    }
    *(float4*)(gpart + (size_t)z * 65536 + base) = acc;
}

// ---------------- finalize g (fp32 + bf16), write common row 0 ----------------
__global__ __launch_bounds__(256) void k_gfinal(const float* __restrict__ gpart,
                                                float* __restrict__ g,
                                                unsigned short* __restrict__ g_bf,
                                                float* __restrict__ common,
                                                unsigned short* __restrict__ common_bf) {
    int idx4 = blockIdx.x * 256 + threadIdx.x;
    size_t base = (size_t)idx4 * 4;
    float4 s = make_float4(0.f, 0.f, 0.f, 0.f);
#pragma unroll
    for (int z = 0; z < 7; z++) {
        float4 v = *(const float4*)(gpart + (size_t)z * 65536 + base);
        s.x += v.x; s.y += v.y; s.z += v.z; s.w += v.w;
    }
    const float r = 1.f / (float)SDIM;
    s.x *= r; s.y *= r; s.z *= r; s.w *= r;
    *(float4*)(g + base) = s;
    ushort4v u;
    u[0] = f2bf(s.x); u[1] = f2bf(s.y); u[2] = f2bf(s.z); u[3] = f2bf(s.w);
    *(ushort4v*)(g_bf + base) = u;
    int b = (int)(base >> 10), d = (int)(base & 1023);
    size_t o = ((size_t)b * 9) * DDIM + d;
    *(float4*)(common + o) = s;
    *(ushort4v*)(common_bf + o) = u;
}

// ---------------- W1 transpose-cast only (rest fused into GEMM stagers) ----------------
__global__ __launch_bounds__(256) void k_prep_w1(const float* __restrict__ uW,
                                                 unsigned short* __restrict__ W1t) {
    __shared__ float tile[64][65];
    int d0 = blockIdx.y * 64, e0 = blockIdx.x * 64, t = threadIdx.x;
    for (int rep = 0; rep < 16; rep++) {
        int idx = rep * 256 + t;
        int dl = idx >> 6, el = idx & 63;
        tile[dl][el] = uW[(size_t)(d0 + dl) * DDIM + e0 + el];
    }
    __syncthreads();
    for (int rep = 0; rep < 16; rep++) {
        int idx = rep * 256 + t;
        int el = idx >> 6, dl = idx & 63;
        W1t[(size_t)(e0 + el) * DDIM + d0 + dl] = f2bf(tile[dl][el]);
    }
}

// ---------------- generic bf16 MFMA GEMM, 64x64 tile, K=1024, ld=1024 ----------------
// A: bf16 [m][k].  B per mode:
//   mode 1: fp32 [n][k]  (cast in stager)
//   mode 2: fp32 [k][n]  (transpose + cast in stager)
// Register-prefetched staging (next K-tile loads issued before the barrier).
__global__ __launch_bounds__(256) void k_mfma64(const unsigned short* __restrict__ A,
                                                const void* __restrict__ B0v,
                                                const void* __restrict__ B1v,
                                                const float* __restrict__ bias0,
                                                const float* __restrict__ bias1,
                                                float* __restrict__ C0,
                                                float* __restrict__ C1,
                                                unsigned short* __restrict__ Cbf,
                                                long sA, long sB, long sBias, long sC,
                                                int zsplit, int mode) {
    __shared__ unsigned short As[64][40];
    __shared__ unsigned short Bs[64][40];
    int z = blockIdx.z;
    const void* Bv; const float* bp; float* Cp; int zz;
    if (z < zsplit) { Bv = B0v; bp = bias0; Cp = C0; zz = z; }
    else            { Bv = B1v; bp = bias1; Cp = C1; zz = z - zsplit; }
    A += (size_t)zz * sA;
    const float* Bf = (const float*)Bv + (size_t)zz * sB;
    if (bp) bp += (size_t)zz * sBias;
    Cp += (size_t)zz * sC;
    unsigned short* Cb = Cbf ? Cbf + (size_t)zz * sC : nullptr;

    int t = threadIdx.x;
    int lane = t & 63, wave = t >> 6;
    int quad = lane >> 4, l16 = lane & 15;
    int wr = wave >> 1, wc = wave & 1;
    int m0 = blockIdx.y * 64, n0 = blockIdx.x * 64;
    f32x4 acc[2][2];
#pragma unroll
    for (int i = 0; i < 2; i++)
#pragma unroll
        for (int j = 0; j < 2; j++)
#pragma unroll
            for (int rr = 0; rr < 4; rr++) acc[i][j][rr] = 0.f;

    int ar = t >> 2, ac = (t & 3) * 8;            // A stage: row, k-offset (8 elems)
    int kr = t >> 4, nc4 = (t & 15) * 4;          // mode-2 B stage: k-row, n-offset (4 elems)

    // prologue: k0 = 0 loads
    ushort8 aR = *(const ushort8*)(A + (size_t)(m0 + ar) * DDIM + ac);
    float4 f0, f1;
    if (mode == 1) {
        f0 = *(const float4*)(Bf + (size_t)(n0 + ar) * DDIM + ac);
        f1 = *(const float4*)(Bf + (size_t)(n0 + ar) * DDIM + ac + 4);
    } else {
        f0 = *(const float4*)(Bf + (size_t)kr * DDIM + n0 + nc4);
        f1 = *(const float4*)(Bf + (size_t)(kr + 16) * DDIM + n0 + nc4);
    }

    for (int k0 = 0; k0 < DDIM; k0 += 32) {
        __syncthreads();   // previous iteration's fragment reads complete
        *(ushort8*)&As[ar][ac] = aR;
        if (mode == 1) {
            ushort8 u;
            u[0] = f2bf(f0.x); u[1] = f2bf(f0.y); u[2] = f2bf(f0.z); u[3] = f2bf(f0.w);
            u[4] = f2bf(f1.x); u[5] = f2bf(f1.y); u[6] = f2bf(f1.z); u[7] = f2bf(f1.w);
            *(ushort8*)&Bs[ar][ac] = u;
        } else {
            Bs[nc4 + 0][kr] = f2bf(f0.x); Bs[nc4 + 1][kr] = f2bf(f0.y);
            Bs[nc4 + 2][kr] = f2bf(f0.z); Bs[nc4 + 3][kr] = f2bf(f0.w);
            Bs[nc4 + 0][kr + 16] = f2bf(f1.x); Bs[nc4 + 1][kr + 16] = f2bf(f1.y);
            Bs[nc4 + 2][kr + 16] = f2bf(f1.z); Bs[nc4 + 3][kr + 16] = f2bf(f1.w);
        }
        int k1 = k0 + 32;
        if (k1 < DDIM) {   // prefetch next K-tile while MFMAs run
            aR = *(const ushort8*)(A + (size_t)(m0 + ar) * DDIM + k1 + ac);
            if (mode == 1) {
                f0 = *(const float4*)(Bf + (size_t)(n0 + ar) * DDIM + k1 + ac);
                f1 = *(const float4*)(Bf + (size_t)(n0 + ar) * DDIM + k1 + ac + 4);
            } else {
                f0 = *(const float4*)(Bf + (size_t)(k1 + kr) * DDIM + n0 + nc4);
                f1 = *(const float4*)(Bf + (size_t)(k1 + kr + 16) * DDIM + n0 + nc4);
            }
        }
        __syncthreads();
        short8 a0 = *(const short8*)&As[wr * 32 + l16][quad * 8];
        short8 a1 = *(const short8*)&As[wr * 32 + 16 + l16][quad * 8];
        short8 b0 = *(const short8*)&Bs[wc * 32 + l16][quad * 8];
        short8 b1 = *(const short8*)&Bs[wc * 32 + 16 + l16][quad * 8];
        acc[0][0] = __builtin_amdgcn_mfma_f32_16x16x32_bf16(a0, b0, acc[0][0], 0, 0, 0);
        acc[0][1] = __builtin_amdgcn_mfma_f32_16x16x32_bf16(a0, b1, acc[0][1], 0, 0, 0);
        acc[1][0] = __builtin_amdgcn_mfma_f32_16x16x32_bf16(a1, b0, acc[1][0], 0, 0, 0);
        acc[1][1] = __builtin_amdgcn_mfma_f32_16x16x32_bf16(a1, b1, acc[1][1], 0, 0, 0);
    }
#pragma unroll
    for (int tm = 0; tm < 2; tm++)
#pragma unroll
        for (int tn = 0; tn < 2; tn++) {
            int col = n0 + wc * 32 + tn * 16 + l16;
            float bb = bp ? bp[col] : 0.f;
#pragma unroll
            for (int rr = 0; rr < 4; rr++) {
                int m = m0 + wr * 32 + tm * 16 + quad * 4 + rr;
                float v = acc[tm][tn][rr] + bb;
                Cp[(size_t)m * DDIM + col] = v;
                if (Cb) Cb[(size_t)m * DDIM + col] = f2bf(v);
            }
        }
}

// ---------------- fused aggregated attention (flash-style over n), grid (8, B) ----------------
// chunk = 64 n rows; partial (m, l, O) per (chunk, b, h) written to ws.
// v2: register prefetch of next 8-row tile — global latency hidden under compute.
__global__ __launch_bounds__(256) void k_agg(const float* __restrict__ gn,
                                             const float* __restrict__ Qt,
                                             const float* __restrict__ Qf,
                                             const float* __restrict__ abk,
                                             float* __restrict__ Opart,
                                             float* __restrict__ ml) {
    int b = blockIdx.y, chunk = blockIdx.x, t = threadIdx.x;
    int wave = t >> 6, lane = t & 63;
    __shared__ float sQt[8][1024];    // 32KB
    __shared__ float srow[8][1024];   // 32KB
    __shared__ float sS[8][8];        // [h][row]
    __shared__ float sEt[8][8];       // [row][h]
    __shared__ float sqkb[8];
    // load Qt[b] rows (layout [h][b][d])
#pragma unroll
    for (int h = 0; h < 8; h++)
        *(float4*)&sQt[h][t * 4] = *(const float4*)(Qt + ((size_t)(h * 64 + b) << 10) + t * 4);
    // qkb[h] = Q[h,b,:]·abk[h,:]  (raw)
    for (int h = wave; h < 8; h += 4) {
        const float* q = Qf + ((size_t)(h * 64 + b) << 10);
        const float* bk = abk + ((size_t)h << 10);
        float a = 0.f;
        for (int e = lane; e < 1024; e += 64) a += q[e] * bk[e];
        a = wred_sum(a);
        if (lane == 0) sqkb[h] = a;
    }
    float O[8][4];
    float m[8], l[8];
#pragma unroll
    for (int h = 0; h < 8; h++) {
        m[h] = -1e30f; l[h] = 0.f;
#pragma unroll
        for (int j = 0; j < 4; j++) O[h][j] = 0.f;
    }
    const float* gnb = gn + (((size_t)b * NDIM + chunk * 64) << 10);
    int r0 = wave * 2, r1 = r0 + 1;

    // prefetch tile 0 into registers
    float4 rv[2][4];
#pragma unroll
    for (int rr = 0; rr < 2; rr++) {
        const float* src = gnb + ((size_t)(wave * 2 + rr) << 10);
#pragma unroll
        for (int j = 0; j < 4; j++) rv[rr][j] = *(const float4*)(src + j * 256 + lane * 4);
    }

    for (int tile = 0; tile < 8; tile++) {
        __syncthreads();   // prev-tile O-update done (srow free); covers sQt/sqkb on tile 0
        // stage this wave's 2 rows from registers
#pragma unroll
        for (int rr = 0; rr < 2; rr++)
#pragma unroll
            for (int j = 0; j < 4; j++)
                *(float4*)&srow[wave * 2 + rr][j * 256 + lane * 4] = rv[rr][j];
        // issue next tile's loads NOW; consumed only at loop end
        float4 nv[2][4];
        if (tile < 7) {
#pragma unroll
            for (int rr = 0; rr < 2; rr++) {
                const float* src = gnb + ((size_t)((tile + 1) * 8 + wave * 2 + rr) << 10);
#pragma unroll
                for (int j = 0; j < 4; j++) nv[rr][j] = *(const float4*)(src + j * 256 + lane * 4);
            }
        }
        // scores for this wave's 2 rows, all 8 heads (fp32, exact; from registers)
#pragma unroll
        for (int h = 0; h < 8; h++) {
            float a0 = 0.f, a1 = 0.f;
#pragma unroll
            for (int j = 0; j < 4; j++) {
                float4 q = *(const float4*)&sQt[h][j * 256 + lane * 4];
                a0 += q.x * rv[0][j].x + q.y * rv[0][j].y + q.z * rv[0][j].z + q.w * rv[0][j].w;
                a1 += q.x * rv[1][j].x + q.y * rv[1][j].y + q.z * rv[1][j].z + q.w * rv[1][j].w;
            }
            a0 = wred_sum(a0); a1 = wred_sum(a1);
            if (lane == 0) {
                sS[h][r0] = (a0 + sqkb[h]) * 0.03125f;
                sS[h][r1] = (a1 + sqkb[h]) * 0.03125f;
            }
        }
        __syncthreads();
        // online-softmax bookkeeping (redundant per thread; identical values)
        float alpha[8];
#pragma unroll
        for (int h = 0; h < 8; h++) {
            float tm = sS[h][0];
#pragma unroll
            for (int r = 1; r < 8; r++) tm = fmaxf(tm, sS[h][r]);
            float mn = fmaxf(m[h], tm);
            alpha[h] = __expf(m[h] - mn);
            m[h] = mn;
        }
        if (t < 64) {
            int r = t >> 3, h = t & 7;
            sEt[r][h] = __expf(sS[h][r] - m[h]);
        }
        __syncthreads();
#pragma unroll
        for (int h = 0; h < 8; h++) {
            l[h] *= alpha[h];
#pragma unroll
            for (int j = 0; j < 4; j++) O[h][j] *= alpha[h];
        }
#pragma unroll
        for (int r = 0; r < 8; r++) {
            float4 e0 = *(const float4*)&sEt[r][0];
            float4 e1 = *(const float4*)&sEt[r][4];
            float4 v = *(const float4*)&srow[r][t * 4];
            float ee[8] = {e0.x, e0.y, e0.z, e0.w, e1.x, e1.y, e1.z, e1.w};
#pragma unroll
            for (int h = 0; h < 8; h++) {
                O[h][0] += ee[h] * v.x; O[h][1] += ee[h] * v.y;
                O[h][2] += ee[h] * v.z; O[h][3] += ee[h] * v.w;
                l[h] += ee[h];
            }
        }
        if (tile < 7) {
#pragma unroll
            for (int rr = 0; rr < 2; rr++)
#pragma unroll
                for (int j = 0; j < 4; j++) rv[rr][j] = nv[rr][j];
        }
    }
    // write partials
    size_t pb = ((size_t)chunk * 64 + b) * 8;
#pragma unroll
    for (int h = 0; h < 8; h++)
        *(float4*)(Opart + (pb + h) * 1024 + t * 4) = make_float4(O[h][0], O[h][1], O[h][2], O[h][3]);
    if (t == 0) {
#pragma unroll
        for (int h = 0; h < 8; h++) {
            ml[(pb + h) * 2 + 0] = m[h];
            ml[(pb + h) * 2 + 1] = l[h];
        }
    }
}

// ---------------- combine 8 chunk-partials -> common rows 1..8 (+bf16) ----------------
__global__ __launch_bounds__(256) void k_agg_reduce(const float* __restrict__ Opart,
                                                    const float* __restrict__ ml,
                                                    float* __restrict__ common,
                                                    unsigned short* __restrict__ common_bf) {
    int b = blockIdx.y, t = threadIdx.x;
    int d = blockIdx.x * 256 + t;
#pragma unroll
    for (int h = 0; h < 8; h++) {
        float mc[8], lc[8];
        float M = -1e30f;
#pragma unroll
        for (int c = 0; c < 8; c++) {
            size_t p = (((size_t)c * 64 + b) * 8 + h) * 2;
            mc[c] = ml[p]; lc[c] = ml[p + 1];
            M = fmaxf(M, mc[c]);
        }
        float den = 0.f, num = 0.f;
#pragma unroll
        for (int c = 0; c < 8; c++) {
            float sc = __expf(mc[c] - M);
            den += sc * lc[c];
            num += sc * Opart[(((size_t)c * 64 + b) * 8 + h) * 1024 + d];
        }
        float o = num / den;
        size_t off = ((size_t)(b * 9 + 1 + h) << 10) + d;
        common[off] = o;
        common_bf[off] = f2bf(o);
    }
}

// ---------------- 9x9 attention + diff -> bf16, grid (B) ----------------
__global__ __launch_bounds__(256) void k_diff(const float* __restrict__ Qd,
                                              const float* __restrict__ Kd,
                                              const float* __restrict__ common,
                                              const float* __restrict__ g,
                                              unsigned short* __restrict__ diffb_bf) {
    int b = blockIdx.x, t = threadIdx.x;
    int wave = t >> 6, lane = t & 63;
    __shared__ float sQ[9 * 1024];
    __shared__ float sK[9 * 1024];
    __shared__ float smd[81];
    __shared__ float sw[9];
    const float* Qb = Qd + (size_t)b * 9216;
    const float* Kb = Kd + (size_t)b * 9216;
    for (int i = t; i < 2304; i += 256) {
        *(float4*)&sQ[i * 4] = *(const float4*)(Qb + (size_t)i * 4);
        *(float4*)&sK[i * 4] = *(const float4*)(Kb + (size_t)i * 4);
    }
    __syncthreads();
    for (int p = wave; p < 81; p += 4) {
        int i = p / 9, j = p % 9;
        const float* qi = sQ + i * 1024;
        const float* kj = sK + j * 1024;
        float a = 0.f;
#pragma unroll
        for (int jj = 0; jj < 4; jj++) {
            float4 q = *(const float4*)(qi + jj * 256 + lane * 4);
            float4 k = *(const float4*)(kj + jj * 256 + lane * 4);
            a += q.x * k.x + q.y * k.y + q.z * k.z + q.w * k.w;
        }
        a = wred_sum(a);
        if (lane == 0) smd[p] = a * 0.03125f;
    }
    __syncthreads();
    if (t < 9) {
        float mx = -1e30f;
        for (int j = 0; j < 9; j++) mx = fmaxf(mx, smd[t * 9 + j]);
        float e[9], s = 0.f;
        for (int j = 0; j < 9; j++) { e[j] = __expf(smd[t * 9 + j] - mx); s += e[j]; }
        float inv = 1.f / s;
        for (int j = 0; j < 9; j++) smd[t * 9 + j] = e[j] * inv;
    }
    __syncthreads();
    if (t < 9) {
        float a = 0.f;
        for (int i = 0; i < 9; i++) a += smd[i * 9 + t];
        sw[t] = a * (1.f / 9.f);
    }
    __syncthreads();
    int d = t * 4;
    float4 ci = make_float4(0.f, 0.f, 0.f, 0.f);
#pragma unroll
    for (int j = 0; j < 9; j++) {
        float w = sw[j];
        float4 cv = *(const float4*)(common + ((size_t)(b * 9 + j) << 10) + d);
        ci.x += w * cv.x; ci.y += w * cv.y; ci.z += w * cv.z; ci.w += w * cv.w;
    }
    float4 gv = *(const float4*)(g + ((size_t)b << 10) + d);
    ushort4v u;
    u[0] = f2bf(gv.x - ci.x); u[1] = f2bf(gv.y - ci.y);
    u[2] = f2bf(gv.z - ci.z); u[3] = f2bf(gv.w - ci.w);
    *(ushort4v*)(diffb_bf + ((size_t)b << 10) + d) = u;
}

// ---------------- main GEMM: relu(Abf@W1t^T + dt2[b]) -> out. 128x128, BK=64, lds-dma ----------------
__global__ __launch_bounds__(256) void k_gemm_main(const unsigned short* __restrict__ A,
                                                   const unsigned short* __restrict__ Bw,
                                                   const float* __restrict__ dt2,
                                                   float* __restrict__ out) {
    __shared__ unsigned short As[128 * 64];
    __shared__ unsigned short Bs[128 * 64];
    int t = threadIdx.x;
    int lane = t & 63, wave = t >> 6;
    int quad = lane >> 4, l16 = lane & 15;
    int wr = wave >> 1, wc = wave & 1;
    int m0 = blockIdx.y * 128, n0 = blockIdx.x * 128;
    f32x4 acc[4][4];
#pragma unroll
    for (int i = 0; i < 4; i++)
#pragma unroll
        for (int j = 0; j < 4; j++)
#pragma unroll
            for (int rr = 0; rr < 4; rr++) acc[i][j][rr] = 0.f;

    for (int k0 = 0; k0 < DDIM; k0 += 64) {
#pragma unroll
        for (int cc = 0; cc < 4; cc++) {
            int o = cc * 4096 + t * 16;
            int r = o >> 7;
            int ke = (o & 127) >> 1;
            __builtin_amdgcn_global_load_lds(
                (gq_ptr)(const void*)(A + (size_t)(m0 + r) * DDIM + k0 + ke),
                (lds_ptr)(void*)((char*)As + o), 16, 0, 0);
            __builtin_amdgcn_global_load_lds(
                (gq_ptr)(const void*)(Bw + (size_t)(n0 + r) * DDIM + k0 + ke),
                (lds_ptr)(void*)((char*)Bs + o), 16, 0, 0);
        }
        __syncthreads();
#pragma unroll
        for (int ks = 0; ks < 2; ks++) {
            short8 af[4], bf[4];
#pragma unroll
            for (int tm = 0; tm < 4; tm++)
                af[tm] = *(const short8*)(As + (wr * 64 + tm * 16 + l16) * 64 + ks * 32 + quad * 8);
#pragma unroll
            for (int tn = 0; tn < 4; tn++)
                bf[tn] = *(const short8*)(Bs + (wc * 64 + tn * 16 + l16) * 64 + ks * 32 + quad * 8);
#pragma unroll
            for (int tm = 0; tm < 4; tm++)
#pragma unroll
                for (int tn = 0; tn < 4; tn++)
                    acc[tm][tn] = __builtin_amdgcn_mfma_f32_16x16x32_bf16(af[tm], bf[tn], acc[tm][tn], 0, 0, 0);
        }
        __syncthreads();
    }
#pragma unroll
    for (int tm = 0; tm < 4; tm++)
#pragma unroll
        for (int tn = 0; tn < 4; tn++) {
            int col = n0 + wc * 64 + tn * 16 + l16;
#pragma unroll
            for (int rr = 0; rr < 4; rr++) {
                int m = m0 + wr * 64 + tm * 16 + quad * 4 + rr;
                float v = acc[tm][tn][rr] + dt2[((size_t)(m & 63) << 10) + col];
                out[((size_t)m << 10) + col] = fmaxf(v, 0.f);
            }
        }
}

// ---------------- in-place LayerNorm over D ----------------
__global__ __launch_bounds__(256) void k_ln(float* __restrict__ io,
                                            const float* __restrict__ gamma,
                                            const float* __restrict__ beta) {
    size_t row = blockIdx.x;
    float* p = io + row * DDIM;
    int t = threadIdx.x;
    float4 v = *(const float4*)(p + t * 4);
    float s = v.x + v.y + v.z + v.w;
    float s2 = v.x * v.x + v.y * v.y + v.z * v.z + v.w * v.w;
    s = wred_sum(s);
    s2 = wred_sum(s2);
    __shared__ float r1[4], r2[4], mv[2];
    int wave = t >> 6, lane = t & 63;
    if (lane == 0) { r1[wave] = s; r2[wave] = s2; }
    __syncthreads();
    if (t == 0) {
        float S = r1[0] + r1[1] + r1[2] + r1[3];
        float S2 = r2[0] + r2[1] + r2[2] + r2[3];
        float mean = S * (1.f / DDIM);
        float var = S2 * (1.f / DDIM) - mean * mean;
        mv[0] = mean;
        mv[1] = rsqrtf(var + 1e-5f);
    }
    __syncthreads();
    float mean = mv[0], rstd = mv[1];
    float4 gg = *(const float4*)(gamma + t * 4);
    float4 bb = *(const float4*)(beta + t * 4);
    float4 o;
    o.x = (v.x - mean) * rstd * gg.x + bb.x;
    o.y = (v.y - mean) * rstd * gg.y + bb.y;
    o.z = (v.z - mean) * rstd * gg.z + bb.z;
    o.w = (v.w - mean) * rstd * gg.w + bb.w;
    *(float4*)(p + t * 4) = o;
}

extern "C" void kernel_launch(void* const* d_in, const int* in_sizes, int n_in,
                              void* d_out, int out_size, void* d_ws, size_t ws_size,
                              hipStream_t stream) {
    (void)in_sizes; (void)n_in; (void)out_size; (void)ws_size;
    const float* input = (const float*)d_in[0];
    const float* gn    = (const float*)d_in[1];
    const float* aWq   = (const float*)d_in[2];
    const float* abq   = (const float*)d_in[3];
    const float* aWk   = (const float*)d_in[4];
    const float* abk   = (const float*)d_in[5];
    const float* dWq   = (const float*)d_in[6];
    const float* dbq   = (const float*)d_in[7];
    const float* dWk   = (const float*)d_in[8];
    const float* dbk   = (const float*)d_in[9];
    const float* uW    = (const float*)d_in[10];
    const float* ub    = (const float*)d_in[11];
    const float* lng   = (const float*)d_in[12];
    const float* lnb   = (const float*)d_in[13];
    float* out = (float*)d_out;

    float* ws = (float*)d_ws;
    float* g      = ws;                       // 65536
    float* gpart  = g + 65536;                // 458752
    float* Q      = gpart + 458752;           // 524288  [h][b][d]
    float* Qt     = Q + 524288;               // 524288  [h][b][d]
    float* common = Qt + 524288;              // 589824  [b][9][d]
    float* dt2    = common + 589824;          // 65536
    float* Opart  = dt2 + 65536;              // 4194304 [c][b][h][d]
    float* ml     = Opart + 4194304;          // 8192
    float* Qd     = Opart;                    // alias: Opart dead after k_agg_reduce
    float* Kd     = Opart + 589824;
    unsigned short* Abf  = (unsigned short*)(ml + 8192);   // 12845056
    unsigned short* W1t  = Abf + 12845056;    // 1048576
    unsigned short* g_bf = W1t + 1048576;     // 65536
    unsigned short* Qbf  = g_bf + 65536;      // 524288
    unsigned short* cmbf = Qbf + 524288;      // 589824
    unsigned short* dfbf = cmbf + 589824;     // 65536

    k_prep_w1<<<dim3(16, 16), 256, 0, stream>>>(uW, W1t);
    k_mean_cast<<<dim3(64, 7), 256, 0, stream>>>(input, Abf, gpart);
    k_gfinal<<<64, 256, 0, stream>>>(gpart, g, g_bf, common, cmbf);
    // Q[h,b,:] = g@aWq[h] + abq[h]  (fp32 + bf16); aWq fp32 [d][e] -> mode 2 transpose-stage
    k_mfma64<<<dim3(16, 1, 8), 256, 0, stream>>>(g_bf, aWq, nullptr, abq, nullptr,
        Q, nullptr, Qbf, 0L, 1048576L, 1024L, 65536L, 8, 2);
    // Qt[h,b,:] = Qbf[h]@aWk[h]^T; aWk fp32 [d][e] consumed as B[n=d][k=e] -> mode 1 cast-stage
    k_mfma64<<<dim3(16, 1, 8), 256, 0, stream>>>(Qbf, aWk, nullptr, nullptr, nullptr,
        Qt, nullptr, nullptr, 65536L, 1048576L, 0L, 65536L, 8, 1);
    k_agg<<<dim3(8, BDIM), 256, 0, stream>>>(gn, Qt, Q, abk, Opart, ml);
    k_agg_reduce<<<dim3(4, BDIM), 256, 0, stream>>>(Opart, ml, common, cmbf);
    // Qd = common@dWq + dbq ; Kd = common@dWk + dbk ; dW* fp32 [d][e] -> mode 2
    k_mfma64<<<dim3(16, 9, 2), 256, 0, stream>>>(cmbf, dWq, dWk, dbq, dbk,
        Qd, Kd, nullptr, 0L, 0L, 0L, 0L, 1, 2);
    k_diff<<<BDIM, 256, 0, stream>>>(Qd, Kd, common, g, dfbf);
    // dt2 = diffb@W2 + ub ; W2 = uW rows 1024..2047, fp32 [d][e] -> mode 2
    k_mfma64<<<dim3(16, 1, 1), 256, 0, stream>>>(dfbf, uW + 1048576, nullptr, ub, nullptr,
        dt2, nullptr, nullptr, 0L, 0L, 0L, 0L, 1, 2);
    k_gemm_main<<<dim3(8, 98), 256, 0, stream>>>(Abf, W1t, dt2, out);
    k_ln<<<SDIM * BDIM, 256, 0, stream>>>(out, lng, lnb);
}